// Round 5
// baseline (230.845 us; speedup 1.0000x reference)
//
#include <hip/hip_runtime.h>

typedef unsigned short ushort_t;
typedef __attribute__((ext_vector_type(8))) short short8;
typedef __attribute__((ext_vector_type(4))) float f32x4;

__device__ __forceinline__ ushort_t f2b(float f) {           // RTN (accurate)
    union { float f; unsigned int i; } v; v.f = f;
    unsigned int x = v.i;
    return (ushort_t)((x + 0x7fffu + ((x >> 16) & 1u)) >> 16);
}
__device__ __forceinline__ ushort_t f2b_fast(float f) {      // round-half-up
    union { float f; unsigned int i; } v; v.f = f;
    return (ushort_t)((v.i + 0x8000u) >> 16);
}
__device__ __forceinline__ float exp2_hw(float x) {          // v_exp_f32: 2^x
    return __builtin_amdgcn_exp2f(x);
}
// async global->LDS DMA, 16B/lane: lane i reads 16B at its own gptr, writes
// LDS at (wave-uniform) lptr + i*16  [m97 recipe]
__device__ __forceinline__ void dma16(const ushort_t* g, ushort_t* l) {
    __builtin_amdgcn_global_load_lds(
        (const __attribute__((address_space(1))) unsigned int*)g,
        (__attribute__((address_space(3))) unsigned int*)l, 16, 0, 0);
}

// ---------------- fp32 -> bf16 conversion pre-pass ------------------------
__global__ __launch_bounds__(256)
void convert_bf16(const float* __restrict__ hs, const float* __restrict__ wq,
                  const float* __restrict__ wk, const float* __restrict__ wv,
                  const float* __restrict__ wo,
                  ushort_t* __restrict__ hsb, ushort_t* __restrict__ wqb,
                  ushort_t* __restrict__ wkb, ushort_t* __restrict__ wvb,
                  ushort_t* __restrict__ wob)
{
    const int y = blockIdx.y;
    const float* src; ushort_t* dst; int n;
    if (y == 0)      { src = hs; dst = hsb; n = 8192 * 768; }
    else if (y == 1) { src = wq; dst = wqb; n = 768 * 768; }
    else if (y == 2) { src = wk; dst = wkb; n = 768 * 768; }
    else if (y == 3) { src = wv; dst = wvb; n = 768 * 768; }
    else             { src = wo; dst = wob; n = 768 * 768; }
    const int idx = (blockIdx.x * 256 + threadIdx.x) * 8;
    if (idx >= n) return;
    const float4 a = ((const float4*)(src + idx))[0];
    const float4 b = ((const float4*)(src + idx))[1];
    ushort_t tmp[8] = { f2b(a.x), f2b(a.y), f2b(a.z), f2b(a.w),
                        f2b(b.x), f2b(b.y), f2b(b.z), f2b(b.w) };
    *(uint4*)(dst + idx) = *(const uint4*)tmp;
}

// ---------------- MFMA GEMM, row-contiguous DMA + XOR-swizzled LDS --------
// (unchanged from round 2 -- verified: row-contiguous 128B DMA spans fixed
// the L2-request bound; gemm no longer the top dispatch)
#define NIT 12    // 768 / BK(=64)

template<int MODE>
__global__ __launch_bounds__(256, 2)
void gemm_mfma(const ushort_t* __restrict__ A,
               const ushort_t* __restrict__ W0, const ushort_t* __restrict__ W1,
               const ushort_t* __restrict__ W2,
               const float* __restrict__ b0, const float* __restrict__ b1,
               const float* __restrict__ b2,
               void* __restrict__ C0, void* __restrict__ C1, void* __restrict__ C2)
{
    __shared__ __attribute__((aligned(16))) ushort_t Ab[2][128 * 64];
    __shared__ __attribute__((aligned(16))) ushort_t Wb[2][128 * 64];

    const int id   = blockIdx.x;
    const int xcd  = id & 7;
    const int slot = id >> 3;
    int mtile, otile, z;
    if (MODE == 0) {
        mtile = (slot / 18) * 8 + xcd;
        const int rem = slot % 18;
        otile = rem % 6;
        z     = rem / 6;
    } else {
        mtile = (slot / 6) * 8 + xcd;
        otile = slot % 6;
        z     = 0;
    }
    const ushort_t* W = (z == 0) ? W0 : (z == 1) ? W1 : W2;
    const float* bias  = (z == 0) ? b0 : (z == 1) ? b1 : b2;
    void* C            = (z == 0) ? C0 : (z == 1) ? C1 : C2;

    const int t    = threadIdx.x;
    const int lane = t & 63;
    const int w    = t >> 6;
    const int col  = lane & 15;
    const int kg   = lane >> 4;
    const int m0   = mtile * 128;
    const int o0   = otile * 128;
    const int mh   = (w & 1) * 64;
    const int oh   = (w >> 1) * 64;

    f32x4 acc[4][4];
#pragma unroll
    for (int mt = 0; mt < 4; ++mt)
#pragma unroll
        for (int nt = 0; nt < 4; ++nt) acc[mt][nt] = (f32x4){0.f, 0.f, 0.f, 0.f};

    // DMA source: lane l covers row (8q + (l>>3)), K-granule (l&7)^(l>>3)
    // of chunk c (instr q in 0..15, wave w owns q = 4w..4w+3).
    const int lrow = lane >> 3;                 // 0..7
    const int lgr  = (lane & 7) ^ lrow;         // pre-swizzled source granule
    const ushort_t* pa = A + (size_t)(m0 + lrow) * 768 + lgr * 8;
    const ushort_t* pw = W + (size_t)(o0 + lrow) * 768 + lgr * 8;

    // bias prefetch (keeps the K-loop free of extra vmem ops)
    float bias_v[4];
#pragma unroll
    for (int nt = 0; nt < 4; ++nt) bias_v[nt] = bias[o0 + oh + nt * 16 + col];

    // stage chunk c (BK=64: rows*128B contiguous) into buffer b
    auto stage = [&](int c, int b) {
#pragma unroll
        for (int j = 0; j < 4; ++j) {
            const int q = 4 * w + j;
            dma16(pa + (size_t)q * (8 * 768) + c * 64, &Ab[b][q * 512]);
            dma16(pw + (size_t)q * (8 * 768) + c * 64, &Wb[b][q * 512]);
        }
    };

    stage(0, 0);   // prologue

    // per-lane swizzled read offsets (ushort units)
    const int c7   = col & 7;
    const int g0   = (kg ^ c7) * 8;             // K-half 0 granule slot
    const int g1   = ((4 + kg) ^ c7) * 8;       // K-half 1 granule slot

#pragma unroll 2
    for (int it = 0; it < NIT; ++it) {
        const int cur = it & 1;
        asm volatile("s_waitcnt vmcnt(0)" ::: "memory");   // chunk it landed
        __builtin_amdgcn_s_barrier();                      // visible to all waves
        if (it + 1 < NIT) stage(it + 1, cur ^ 1);          // next chunk flies over body

        short8 wf[4][2], af[4][2];
#pragma unroll
        for (int nt = 0; nt < 4; ++nt) {
            const int r = (oh + nt * 16 + col) * 64;
            wf[nt][0] = *(const short8*)&Wb[cur][r + g0];
            wf[nt][1] = *(const short8*)&Wb[cur][r + g1];
        }
#pragma unroll
        for (int mt = 0; mt < 4; ++mt) {
            const int r = (mh + mt * 16 + col) * 64;
            af[mt][0] = *(const short8*)&Ab[cur][r + g0];
            af[mt][1] = *(const short8*)&Ab[cur][r + g1];
        }

#pragma unroll
        for (int mt = 0; mt < 4; ++mt)
#pragma unroll
            for (int nt = 0; nt < 4; ++nt) {
                acc[mt][nt] = __builtin_amdgcn_mfma_f32_16x16x32_bf16(
                    af[mt][0], wf[nt][0], acc[mt][nt], 0, 0, 0);
                acc[mt][nt] = __builtin_amdgcn_mfma_f32_16x16x32_bf16(
                    af[mt][1], wf[nt][1], acc[mt][nt], 0, 0, 0);
            }
    }

    // Q prescale: 1/8 (attn scale) * log2(e), so attn softmax can use exp2
    const float scale = (MODE == 0 && z == 0) ? 0.18033688011112042f : 1.0f;

#pragma unroll
    for (int mt = 0; mt < 4; ++mt)
#pragma unroll
        for (int nt = 0; nt < 4; ++nt) {
            const int mb = m0 + mh + mt * 16 + kg * 4;
            const int o  = o0 + oh + nt * 16 + col;
            if (MODE == 0 && z == 2) {
                ushort_t tmp[4];
#pragma unroll
                for (int r = 0; r < 4; ++r) tmp[r] = f2b(acc[mt][nt][r] + bias_v[nt]);
                const size_t dst = ((size_t)((mb >> 11) * 12 + (o >> 6)) << 17)
                                 + ((size_t)(o & 63) << 11) + (mb & 2047);
                *(uint2*)((ushort_t*)C + dst) = *(const uint2*)tmp;
            } else {
#pragma unroll
                for (int r = 0; r < 4; ++r) {
                    const int m = mb + r;
                    const float v = (acc[mt][nt][r] + bias_v[nt]) * scale;
                    if (MODE == 0) {
                        const size_t dst = ((size_t)((m >> 11) * 12 + (o >> 6)) << 17)
                                         + ((size_t)(m & 2047) << 6) + (o & 63);
                        ((ushort_t*)C)[dst] = f2b(v);
                    } else {
                        ((float*)C)[(size_t)m * 768 + o] = v;
                    }
                }
            }
        }
}

// ---------------- MFMA flash attention, deferred-PV pipeline --------------
// Q: [48][2048][64] bf16 pre-scaled by 0.125*log2e. K: [48][2048][64].
// Vt: [48][64][2048]. AO: [4][2048][768] bf16.
// ROUND-5: r4 (fewer barriers) was neutral -> binder is the per-chunk
// INTRA-WAVE chain: Kread->QKT->exp2->Ps write->lgkm->Ps read->Vread->PV.
// Fix (T15): PV runs ONE CHUNK LATE. Iter c: QKT(c)+softmax(c)->Ps[c&1],
// and PV(c-1) from Ps[c&1^1]+Vs[c&1^1] whose inputs are final since last
// iter -> PV's ds_reads/MFMAs have zero waits and overlap QKT's latency.
// Ks single-buffered (same-iter use, 2-barrier protected as r2);
// Vs double (consumed next iter); Ps per-wave double (no sync needed).
// LDS 47KB -> 3 blocks/CU (residency unchanged; isolates the chain effect).
#define KV_STRIDE 72
#define PS_STRIDE 76

__global__ __launch_bounds__(256, 3)
void attn_mfma(const ushort_t* __restrict__ Q, const ushort_t* __restrict__ K,
               const ushort_t* __restrict__ Vt, ushort_t* __restrict__ AO)
{
    __shared__ ushort_t Ks[64 * KV_STRIDE];        // K chunk [key][d]
    __shared__ ushort_t Vs[2][64 * KV_STRIDE];     // V chunk [d][key], dbuf
    __shared__ ushort_t Ps[4][2][16 * PS_STRIDE];  // per-wave P tile, dbuf

    const int t    = threadIdx.x;
    const int lane = t & 63;
    const int w    = t >> 6;
    const int id   = blockIdx.x;
    const int bh   = ((id >> 3) >> 4) * 8 + (id & 7);   // 16 blocks/bh on one XCD
    const int p    = (id >> 3) & 15;                    // pair id 0..15
    const size_t base = (size_t)bh << 17;

    const int col = lane & 15;
    const int kg  = lane >> 4;
    const int srow = t >> 2;                       // staging row 0..63
    const int scol = (t & 3) << 4;                 // staging col 0/16/32/48
    const int b = bh / 12, h = bh % 12;

#pragma unroll
    for (int phase = 0; phase < 2; ++phase) {
        const int tile = phase ? p : (31 - p);     // heavy tile first
        const int q0   = tile << 6;
        const int nch  = tile + 1;

        // Q A-frag for this wave's 16 rows
        const ushort_t* pq = Q + base + (size_t)(q0 + 16 * w + col) * 64 + kg * 8;
        const short8 aq0 = *(const short8*)pq;
        const short8 aq1 = *(const short8*)(pq + 32);

        float l_lane[4] = {0.f, 0.f, 0.f, 0.f};
        f32x4 o_acc[4];
#pragma unroll
        for (int vt = 0; vt < 4; ++vt) o_acc[vt] = (f32x4){0.f, 0.f, 0.f, 0.f};

        // protect Ks/Vs from the previous phase's pending epilogue reads
        __syncthreads();

        // prologue: load + stage chunk 0 (Ks, Vs[0])
        {
            const ushort_t* pk = K  + base + (size_t)srow * 64 + scol;
            const ushort_t* pv = Vt + base + ((size_t)srow << 11) + scol;
            const uint4 ka = *(const uint4*)pk, kb = *(const uint4*)(pk + 8);
            const uint4 va = *(const uint4*)pv, vb = *(const uint4*)(pv + 8);
            *(uint4*)&Ks[srow * KV_STRIDE + scol]        = ka;
            *(uint4*)&Ks[srow * KV_STRIDE + scol + 8]    = kb;
            *(uint4*)&Vs[0][srow * KV_STRIDE + scol]     = va;
            *(uint4*)&Vs[0][srow * KV_STRIDE + scol + 8] = vb;
        }

        for (int c = 0; c < nch; ++c) {
            const int cur = c & 1, prv = cur ^ 1;
            __syncthreads();   // staging(c) visible to all waves

            // issue next chunk's global loads early (hide under compute)
            uint4 ka, kb, va, vb;
            if (c + 1 < nch) {
                const int k1 = (c + 1) << 6;
                const ushort_t* pk = K  + base + (size_t)(k1 + srow) * 64 + scol;
                const ushort_t* pv = Vt + base + ((size_t)srow << 11) + k1 + scol;
                ka = *(const uint4*)pk; kb = *(const uint4*)(pk + 8);
                va = *(const uint4*)pv; vb = *(const uint4*)(pv + 8);
            }

            // ---- PV(c-1): inputs finalized last iter -> zero-wait MFMAs ----
            if (c > 0) {
                short8 pa0, pa1;
                {
                    const ushort_t* pp = Ps[w][prv] + (size_t)col * PS_STRIDE + kg * 8;
                    pa0 = *(const short8*)pp;
                    pa1 = *(const short8*)(pp + 32);
                }
                __builtin_amdgcn_s_setprio(1);
#pragma unroll
                for (int vt = 0; vt < 4; ++vt) {
                    const ushort_t* pvf = &Vs[prv][(vt * 16 + col) * KV_STRIDE + kg * 8];
                    const short8 v0 = *(const short8*)pvf;
                    const short8 v1 = *(const short8*)(pvf + 32);
                    f32x4 o = o_acc[vt];
                    o = __builtin_amdgcn_mfma_f32_16x16x32_bf16(pa0, v0, o, 0, 0, 0);
                    o = __builtin_amdgcn_mfma_f32_16x16x32_bf16(pa1, v1, o, 0, 0, 0);
                    o_acc[vt] = o;
                }
                __builtin_amdgcn_s_setprio(0);
            }

            // ---- QK^T(c) ----
            f32x4 s[4];
            __builtin_amdgcn_s_setprio(1);
#pragma unroll
            for (int kt = 0; kt < 4; ++kt) {
                const ushort_t* pkf = &Ks[(kt * 16 + col) * KV_STRIDE + kg * 8];
                const short8 b0 = *(const short8*)pkf;
                const short8 b1 = *(const short8*)(pkf + 32);
                f32x4 acc = (f32x4){0.f, 0.f, 0.f, 0.f};
                acc = __builtin_amdgcn_mfma_f32_16x16x32_bf16(aq0, b0, acc, 0, 0, 0);
                acc = __builtin_amdgcn_mfma_f32_16x16x32_bf16(aq1, b1, acc, 0, 0, 0);
                s[kt] = acc;
            }
            __builtin_amdgcn_s_setprio(0);

            // P = exp2(S); causal mask only on the diagonal (last) chunk
            const int qrow = q0 + 16 * w + 4 * kg;
            if (c == nch - 1) {
                const int k0 = c << 6;
#pragma unroll
                for (int kt = 0; kt < 4; ++kt)
#pragma unroll
                    for (int r = 0; r < 4; ++r) {
                        const int key = k0 + kt * 16 + col;
                        s[kt][r] = (key > qrow + r) ? 0.f : exp2_hw(s[kt][r]);
                    }
            } else {
#pragma unroll
                for (int kt = 0; kt < 4; ++kt)
#pragma unroll
                    for (int r = 0; r < 4; ++r) s[kt][r] = exp2_hw(s[kt][r]);
            }
#pragma unroll
            for (int r = 0; r < 4; ++r)
                l_lane[r] += (s[0][r] + s[1][r]) + (s[2][r] + s[3][r]);

            // P(c) -> Ps[w][cur] (wave-private; consumed next iter)
            {
                ushort_t* ps = Ps[w][cur];
#pragma unroll
                for (int kt = 0; kt < 4; ++kt)
#pragma unroll
                    for (int r = 0; r < 4; ++r)
                        ps[(4 * kg + r) * PS_STRIDE + kt * 16 + col] = f2b_fast(s[kt][r]);
            }

            // stage chunk c+1 (Ks overwrite + Vs[prv]): needs all iter-c
            // Ks reads and iter-(c-1) Vs[prv] reads drained -> barrier
            if (c + 1 < nch) {
                __syncthreads();
                *(uint4*)&Ks[srow * KV_STRIDE + scol]          = ka;
                *(uint4*)&Ks[srow * KV_STRIDE + scol + 8]      = kb;
                *(uint4*)&Vs[prv][srow * KV_STRIDE + scol]     = va;
                *(uint4*)&Vs[prv][srow * KV_STRIDE + scol + 8] = vb;
            }
        }

        // ---- final deferred PV(nch-1) ----
        {
            const int pb = (nch - 1) & 1;
            short8 pa0, pa1;
            {
                const ushort_t* pp = Ps[w][pb] + (size_t)col * PS_STRIDE + kg * 8;
                pa0 = *(const short8*)pp;
                pa1 = *(const short8*)(pp + 32);
            }
            __builtin_amdgcn_s_setprio(1);
#pragma unroll
            for (int vt = 0; vt < 4; ++vt) {
                const ushort_t* pvf = &Vs[pb][(vt * 16 + col) * KV_STRIDE + kg * 8];
                const short8 v0 = *(const short8*)pvf;
                const short8 v1 = *(const short8*)(pvf + 32);
                f32x4 o = o_acc[vt];
                o = __builtin_amdgcn_mfma_f32_16x16x32_bf16(pa0, v0, o, 0, 0, 0);
                o = __builtin_amdgcn_mfma_f32_16x16x32_bf16(pa1, v1, o, 0, 0, 0);
                o_acc[vt] = o;
            }
            __builtin_amdgcn_s_setprio(0);
        }

        // l reduction (once per phase) + normalize + store
        float linv[4];
#pragma unroll
        for (int r = 0; r < 4; ++r) {
            float ls = l_lane[r];
            ls += __shfl_xor(ls, 1);
            ls += __shfl_xor(ls, 2);
            ls += __shfl_xor(ls, 4);
            ls += __shfl_xor(ls, 8);
            linv[r] = 1.f / ls;
        }
#pragma unroll
        for (int vt = 0; vt < 4; ++vt)
#pragma unroll
            for (int r = 0; r < 4; ++r) {
                const int q = q0 + 16 * w + 4 * kg + r;
                AO[((size_t)(b * 2048 + q)) * 768 + h * 64 + vt * 16 + col] =
                    f2b_fast(o_acc[vt][r] * linv[r]);
            }
    }
}

extern "C" void kernel_launch(void* const* d_in, const int* in_sizes, int n_in,
                              void* d_out, int out_size, void* d_ws, size_t ws_size,
                              hipStream_t stream) {
    const float* hs = (const float*)d_in[0];
    const float* wq = (const float*)d_in[1];
    const float* bq = (const float*)d_in[2];
    const float* wk = (const float*)d_in[3];
    const float* bk = (const float*)d_in[4];
    const float* wv = (const float*)d_in[5];
    const float* bv = (const float*)d_in[6];
    const float* wo = (const float*)d_in[7];
    const float* bo = (const float*)d_in[8];
    float* out = (float*)d_out;

    const size_t NB = (size_t)8192 * 768;
    const size_t WN = (size_t)768 * 768;
    ushort_t* hsb = (ushort_t*)d_ws;        // aliased: becomes AO after QKV GEMMs
    ushort_t* Qb  = hsb + NB;
    ushort_t* Kb  = Qb + NB;
    ushort_t* Vtb = Kb + NB;                // V transposed [48][64][2048]
    ushort_t* wqb = Vtb + NB;
    ushort_t* wkb = wqb + WN;
    ushort_t* wvb = wkb + WN;
    ushort_t* wob = wvb + WN;
    ushort_t* AO  = hsb;                    // hs_bf16 dead once attn runs

    dim3 blk(256);
    convert_bf16<<<dim3(3072, 5), blk, 0, stream>>>(hs, wq, wk, wv, wo,
                                                    hsb, wqb, wkb, wvb, wob);
    gemm_mfma<0><<<dim3(1152), blk, 0, stream>>>(hsb, wqb, wkb, wvb,
                                                 bq, bk, bv, Qb, Kb, Vtb);
    attn_mfma<<<dim3(768), blk, 0, stream>>>(Qb, Kb, Vtb, AO);
    gemm_mfma<1><<<dim3(384), blk, 0, stream>>>(AO, wob, wob, wob,
                                                bo, bo, bo, out, out, out);
}

// Round 6
// 227.559 us; speedup vs baseline: 1.0144x; 1.0144x over previous
//
#include <hip/hip_runtime.h>

typedef unsigned short ushort_t;
typedef __attribute__((ext_vector_type(8))) short short8;
typedef __attribute__((ext_vector_type(4))) float f32x4;

__device__ __forceinline__ ushort_t f2b(float f) {           // RTN (accurate)
    union { float f; unsigned int i; } v; v.f = f;
    unsigned int x = v.i;
    return (ushort_t)((x + 0x7fffu + ((x >> 16) & 1u)) >> 16);
}
__device__ __forceinline__ ushort_t f2b_fast(float f) {      // round-half-up
    union { float f; unsigned int i; } v; v.f = f;
    return (ushort_t)((v.i + 0x8000u) >> 16);
}
__device__ __forceinline__ float exp2_hw(float x) {          // v_exp_f32: 2^x
    return __builtin_amdgcn_exp2f(x);
}
// async global->LDS DMA, 16B/lane: lane i reads 16B at its own gptr, writes
// LDS at (wave-uniform) lptr + i*16  [m97 recipe]
__device__ __forceinline__ void dma16(const ushort_t* g, ushort_t* l) {
    __builtin_amdgcn_global_load_lds(
        (const __attribute__((address_space(1))) unsigned int*)g,
        (__attribute__((address_space(3))) unsigned int*)l, 16, 0, 0);
}

// ---------------- fp32 -> bf16 conversion pre-pass ------------------------
__global__ __launch_bounds__(256)
void convert_bf16(const float* __restrict__ hs, const float* __restrict__ wq,
                  const float* __restrict__ wk, const float* __restrict__ wv,
                  const float* __restrict__ wo,
                  ushort_t* __restrict__ hsb, ushort_t* __restrict__ wqb,
                  ushort_t* __restrict__ wkb, ushort_t* __restrict__ wvb,
                  ushort_t* __restrict__ wob)
{
    const int y = blockIdx.y;
    const float* src; ushort_t* dst; int n;
    if (y == 0)      { src = hs; dst = hsb; n = 8192 * 768; }
    else if (y == 1) { src = wq; dst = wqb; n = 768 * 768; }
    else if (y == 2) { src = wk; dst = wkb; n = 768 * 768; }
    else if (y == 3) { src = wv; dst = wvb; n = 768 * 768; }
    else             { src = wo; dst = wob; n = 768 * 768; }
    const int idx = (blockIdx.x * 256 + threadIdx.x) * 8;
    if (idx >= n) return;
    const float4 a = ((const float4*)(src + idx))[0];
    const float4 b = ((const float4*)(src + idx))[1];
    ushort_t tmp[8] = { f2b(a.x), f2b(a.y), f2b(a.z), f2b(a.w),
                        f2b(b.x), f2b(b.y), f2b(b.z), f2b(b.w) };
    *(uint4*)(dst + idx) = *(const uint4*)tmp;
}

// ---------------- MFMA GEMM: BK=32, 3-buffer, COUNTED vmcnt (T3/T4) -------
// C[m,o] = sum_k A[m,k]*W[o,k] + bias[o].  Block 256 thr / 4 waves;
// tile 128(m) x 128(o) x BK=32; wave tile 64x64 (16 MFMA/iter); 24 K-iters.
// ROUND-6: r2 drained vmcnt(0) every iter (T4 violation) at 2 blocks/CU.
// Now: 3 chunk buffers (48KB LDS -> 3 blocks/CU) and per iter:
//   s_barrier -> issue chunk it+2 DMAs -> s_waitcnt vmcnt(8)
// (chunk it retired; chunks it+1,it+2 = 8 ops stay in flight). vmcnt never
// drains to 0 in the main loop; chunk flight = 2 full bodies >= L2 latency.
// DMA stays row-contiguous: 16 rows x 64B full cache lines per instr.
// Swizzle (64B rows, 4 granules): LDS slot (row,gs) holds granule
// gs ^ ((row>>1)&3); source lane l fetches granule (l&3)^((l>>3)&3);
// read slot = kg ^ ((col>>1)&3)  -> 8 distinct bank-starts, conflict-free.
// 1-D grid, id = (slot << 3) | xcd: blocks sharing an A m-tile on one XCD.
// MODE 0 (QKV): 1152 blocks. z=0 -> Q [bh][l][64] * (0.125*log2e);
//   z=1 -> K [bh][l][64]; z=2 -> V transposed [bh][64][l]
// MODE 1 (out-proj): 384 blocks; C fp32 [m][768].
#define NIT 24    // 768 / BK(=32)

template<int MODE>
__global__ __launch_bounds__(256, 3)
void gemm_mfma(const ushort_t* __restrict__ A,
               const ushort_t* __restrict__ W0, const ushort_t* __restrict__ W1,
               const ushort_t* __restrict__ W2,
               const float* __restrict__ b0, const float* __restrict__ b1,
               const float* __restrict__ b2,
               void* __restrict__ C0, void* __restrict__ C1, void* __restrict__ C2)
{
    __shared__ __attribute__((aligned(16))) ushort_t Ab[3][128 * 32];
    __shared__ __attribute__((aligned(16))) ushort_t Wb[3][128 * 32];

    const int id   = blockIdx.x;
    const int xcd  = id & 7;
    const int slot = id >> 3;
    int mtile, otile, z;
    if (MODE == 0) {
        mtile = (slot / 18) * 8 + xcd;
        const int rem = slot % 18;
        otile = rem % 6;
        z     = rem / 6;
    } else {
        mtile = (slot / 6) * 8 + xcd;
        otile = slot % 6;
        z     = 0;
    }
    const ushort_t* W = (z == 0) ? W0 : (z == 1) ? W1 : W2;
    const float* bias  = (z == 0) ? b0 : (z == 1) ? b1 : b2;
    void* C            = (z == 0) ? C0 : (z == 1) ? C1 : C2;

    const int t    = threadIdx.x;
    const int lane = t & 63;
    const int w    = t >> 6;
    const int col  = lane & 15;
    const int kg   = lane >> 4;
    const int m0   = mtile * 128;
    const int o0   = otile * 128;
    const int mh   = (w & 1) * 64;
    const int oh   = (w >> 1) * 64;

    f32x4 acc[4][4];
#pragma unroll
    for (int mt = 0; mt < 4; ++mt)
#pragma unroll
        for (int nt = 0; nt < 4; ++nt) acc[mt][nt] = (f32x4){0.f, 0.f, 0.f, 0.f};

    // DMA source: instr q covers rows 16q..16q+15 (64B/row, full lines).
    // lane l: row_in = l>>2, fetched granule (l&3)^((l>>3)&3) (pre-swizzle).
    const int lrow = lane >> 2;                       // 0..15
    const int lgr  = (lane & 3) ^ ((lane >> 3) & 3);  // source granule
    const ushort_t* pa = A + (size_t)(m0 + lrow) * 768 + lgr * 8;
    const ushort_t* pw = W + (size_t)(o0 + lrow) * 768 + lgr * 8;

    // stage chunk c into buffer b: 2 instrs/array/wave (q = 2w, 2w+1)
    auto stage = [&](int c, int b) {
#pragma unroll
        for (int j = 0; j < 2; ++j) {
            const int q = 2 * w + j;
            dma16(pa + (size_t)q * (16 * 768) + c * 32, &Ab[b][q * 512]);
            dma16(pw + (size_t)q * (16 * 768) + c * 32, &Wb[b][q * 512]);
        }
    };

    // per-lane swizzled read granule slot (ushort offset)
    const int gq = (kg ^ ((col >> 1) & 3)) * 8;

    auto step = [&](int it, int cur, int nb) {
        __builtin_amdgcn_s_barrier();      // all waves done reading buf[nb]
        if (it + 2 < NIT) {
            stage(it + 2, nb);             // 4 ops; chunks it+1,it+2 in flight
            asm volatile("s_waitcnt vmcnt(8)" ::: "memory");   // chunk it landed
        } else if (it + 1 < NIT) {
            asm volatile("s_waitcnt vmcnt(4)" ::: "memory");
        } else {
            asm volatile("s_waitcnt vmcnt(0)" ::: "memory");
        }
        __builtin_amdgcn_sched_barrier(0);

        short8 wf[4], af[4];
#pragma unroll
        for (int nt = 0; nt < 4; ++nt)
            wf[nt] = *(const short8*)&Wb[cur][(oh + nt * 16 + col) * 32 + gq];
#pragma unroll
        for (int mt = 0; mt < 4; ++mt)
            af[mt] = *(const short8*)&Ab[cur][(mh + mt * 16 + col) * 32 + gq];

#pragma unroll
        for (int mt = 0; mt < 4; ++mt)
#pragma unroll
            for (int nt = 0; nt < 4; ++nt)
                acc[mt][nt] = __builtin_amdgcn_mfma_f32_16x16x32_bf16(
                    af[mt], wf[nt], acc[mt][nt], 0, 0, 0);
    };

    stage(0, 0);   // prologue: chunks 0,1 -> 8 ops outstanding
    stage(1, 1);
    for (int j = 0; j < NIT; j += 3) {     // static buffer rotation
        step(j + 0, 0, 2);
        step(j + 1, 1, 0);
        step(j + 2, 2, 1);
    }

    // bias loaded AFTER the loop (keeps vmcnt = DMA-only in the main loop)
    float bias_v[4];
#pragma unroll
    for (int nt = 0; nt < 4; ++nt) bias_v[nt] = bias[o0 + oh + nt * 16 + col];
    // Q prescale: 1/8 (attn scale) * log2(e), so attn softmax can use exp2
    const float scale = (MODE == 0 && z == 0) ? 0.18033688011112042f : 1.0f;

#pragma unroll
    for (int mt = 0; mt < 4; ++mt)
#pragma unroll
        for (int nt = 0; nt < 4; ++nt) {
            const int mb = m0 + mh + mt * 16 + kg * 4;
            const int o  = o0 + oh + nt * 16 + col;
            if (MODE == 0 && z == 2) {
                ushort_t tmp[4];
#pragma unroll
                for (int r = 0; r < 4; ++r) tmp[r] = f2b(acc[mt][nt][r] + bias_v[nt]);
                const size_t dst = ((size_t)((mb >> 11) * 12 + (o >> 6)) << 17)
                                 + ((size_t)(o & 63) << 11) + (mb & 2047);
                *(uint2*)((ushort_t*)C + dst) = *(const uint2*)tmp;
            } else {
#pragma unroll
                for (int r = 0; r < 4; ++r) {
                    const int m = mb + r;
                    const float v = (acc[mt][nt][r] + bias_v[nt]) * scale;
                    if (MODE == 0) {
                        const size_t dst = ((size_t)((m >> 11) * 12 + (o >> 6)) << 17)
                                         + ((size_t)(m & 2047) << 6) + (o & 63);
                        ((ushort_t*)C)[dst] = f2b(v);
                    } else {
                        ((float*)C)[(size_t)m * 768 + o] = v;
                    }
                }
            }
        }
}

// ---------------- MFMA flash attention (round-2 structure, verified best) -
// Q: [48][2048][64] bf16 pre-scaled by 0.125*log2e. K: [48][2048][64].
// Vt: [48][64][2048]. AO: [4][2048][768] bf16.
// 1-D grid of 768; 16 pair-blocks of one bh land on one XCD (K/V L2-resident).
// Block = 2 paired 64-row q-tiles (31-p, p) -> uniform 33 chunks per block.
// ROUND-6 change: PS_STRIDE 76 -> 78. The Ps read (col*PS_STRIDE) at 76
// gives stride 38 dwords == 6 mod 32 (gcd 2): all 64 lanes start on EVEN
// banks -> ~2-way conflict. 78 -> 39 dw == 7 mod 32 (odd, bijective over
// 16 cols) -> mixed-parity starts, conflict-free. (r4/r5 pipeline
// restructures measured neutral -> reverted to this r2 structure.)
#define KV_STRIDE 72
#define PS_STRIDE 78

__global__ __launch_bounds__(256, 3)
void attn_mfma(const ushort_t* __restrict__ Q, const ushort_t* __restrict__ K,
               const ushort_t* __restrict__ Vt, ushort_t* __restrict__ AO)
{
    __shared__ ushort_t Ks[64 * KV_STRIDE];        // K chunk [key][d]
    __shared__ ushort_t Vs[64 * KV_STRIDE];        // V chunk [d][key]
    __shared__ ushort_t Ps[4][16 * PS_STRIDE];     // per-wave P tile [q][key]

    const int t    = threadIdx.x;
    const int lane = t & 63;
    const int w    = t >> 6;
    const int id   = blockIdx.x;
    const int bh   = ((id >> 3) >> 4) * 8 + (id & 7);   // 16 blocks/bh on one XCD
    const int p    = (id >> 3) & 15;                    // pair id 0..15
    const size_t base = (size_t)bh << 17;

    const int col = lane & 15;
    const int kg  = lane >> 4;
    const int srow = t >> 2;                       // staging row 0..63
    const int scol = (t & 3) << 4;                 // staging col 0/16/32/48
    const int b = bh / 12, h = bh % 12;

#pragma unroll
    for (int phase = 0; phase < 2; ++phase) {
        const int tile = phase ? p : (31 - p);     // heavy tile first
        const int q0   = tile << 6;
        const int nch  = tile + 1;

        // Q A-frag for this wave's 16 rows
        const ushort_t* pq = Q + base + (size_t)(q0 + 16 * w + col) * 64 + kg * 8;
        const short8 aq0 = *(const short8*)pq;
        const short8 aq1 = *(const short8*)(pq + 32);

        float l_lane[4] = {0.f, 0.f, 0.f, 0.f};
        f32x4 o_acc[4];
#pragma unroll
        for (int vt = 0; vt < 4; ++vt) o_acc[vt] = (f32x4){0.f, 0.f, 0.f, 0.f};

        // preload chunk 0
        uint4 ka, kb, va, vb;
        {
            const ushort_t* pk = K  + base + (size_t)srow * 64 + scol;
            const ushort_t* pv = Vt + base + ((size_t)srow << 11) + scol;
            ka = *(const uint4*)pk; kb = *(const uint4*)(pk + 8);
            va = *(const uint4*)pv; vb = *(const uint4*)(pv + 8);
        }

        for (int c = 0; c < nch; ++c) {
            __syncthreads();   // previous chunk's LDS reads complete
            *(uint4*)&Ks[srow * KV_STRIDE + scol]     = ka;
            *(uint4*)&Ks[srow * KV_STRIDE + scol + 8] = kb;
            *(uint4*)&Vs[srow * KV_STRIDE + scol]     = va;
            *(uint4*)&Vs[srow * KV_STRIDE + scol + 8] = vb;
            __syncthreads();   // chunk staged

            if (c + 1 < nch) {   // prefetch next chunk (overlaps compute)
                const int k1 = (c + 1) << 6;
                const ushort_t* pk = K  + base + (size_t)(k1 + srow) * 64 + scol;
                const ushort_t* pv = Vt + base + ((size_t)srow << 11) + k1 + scol;
                ka = *(const uint4*)pk; kb = *(const uint4*)(pk + 8);
                va = *(const uint4*)pv; vb = *(const uint4*)(pv + 8);
            }

            // S = (Q * 0.125*log2e) K^T
            f32x4 s[4];
            __builtin_amdgcn_s_setprio(1);
#pragma unroll
            for (int kt = 0; kt < 4; ++kt) {
                const ushort_t* pkf = &Ks[(kt * 16 + col) * KV_STRIDE + kg * 8];
                const short8 b0 = *(const short8*)pkf;
                const short8 b1 = *(const short8*)(pkf + 32);
                f32x4 acc = (f32x4){0.f, 0.f, 0.f, 0.f};
                acc = __builtin_amdgcn_mfma_f32_16x16x32_bf16(aq0, b0, acc, 0, 0, 0);
                acc = __builtin_amdgcn_mfma_f32_16x16x32_bf16(aq1, b1, acc, 0, 0, 0);
                s[kt] = acc;
            }
            __builtin_amdgcn_s_setprio(0);

            // P = exp2(S); causal mask only on the diagonal (last) chunk
            const int qrow = q0 + 16 * w + 4 * kg;
            if (c == nch - 1) {
                const int k0 = c << 6;
#pragma unroll
                for (int kt = 0; kt < 4; ++kt)
#pragma unroll
                    for (int r = 0; r < 4; ++r) {
                        const int key = k0 + kt * 16 + col;
                        s[kt][r] = (key > qrow + r) ? 0.f : exp2_hw(s[kt][r]);
                    }
            } else {
#pragma unroll
                for (int kt = 0; kt < 4; ++kt)
#pragma unroll
                    for (int r = 0; r < 4; ++r) s[kt][r] = exp2_hw(s[kt][r]);
            }
#pragma unroll
            for (int r = 0; r < 4; ++r)
                l_lane[r] += (s[0][r] + s[1][r]) + (s[2][r] + s[3][r]);

            // P: C-layout -> LDS -> A-layout (wave-internal)
            ushort_t* ps = Ps[w];
#pragma unroll
            for (int kt = 0; kt < 4; ++kt)
#pragma unroll
                for (int r = 0; r < 4; ++r)
                    ps[(4 * kg + r) * PS_STRIDE + kt * 16 + col] = f2b_fast(s[kt][r]);
            short8 pa0, pa1;
            {
                const ushort_t* pp = ps + (size_t)col * PS_STRIDE + kg * 8;
                pa0 = *(const short8*)pp;
                pa1 = *(const short8*)(pp + 32);
            }

            // O += P V
            __builtin_amdgcn_s_setprio(1);
#pragma unroll
            for (int vt = 0; vt < 4; ++vt) {
                const ushort_t* pvf = &Vs[(vt * 16 + col) * KV_STRIDE + kg * 8];
                const short8 v0 = *(const short8*)pvf;
                const short8 v1 = *(const short8*)(pvf + 32);
                f32x4 o = o_acc[vt];
                o = __builtin_amdgcn_mfma_f32_16x16x32_bf16(pa0, v0, o, 0, 0, 0);
                o = __builtin_amdgcn_mfma_f32_16x16x32_bf16(pa1, v1, o, 0, 0, 0);
                o_acc[vt] = o;
            }
            __builtin_amdgcn_s_setprio(0);
        }

        // l reduction (once per phase) + normalize + store
        float linv[4];
#pragma unroll
        for (int r = 0; r < 4; ++r) {
            float ls = l_lane[r];
            ls += __shfl_xor(ls, 1);
            ls += __shfl_xor(ls, 2);
            ls += __shfl_xor(ls, 4);
            ls += __shfl_xor(ls, 8);
            linv[r] = 1.f / ls;
        }
#pragma unroll
        for (int vt = 0; vt < 4; ++vt)
#pragma unroll
            for (int r = 0; r < 4; ++r) {
                const int q = q0 + 16 * w + 4 * kg + r;
                AO[((size_t)(b * 2048 + q)) * 768 + h * 64 + vt * 16 + col] =
                    f2b_fast(o_acc[vt][r] * linv[r]);
            }
    }
}

extern "C" void kernel_launch(void* const* d_in, const int* in_sizes, int n_in,
                              void* d_out, int out_size, void* d_ws, size_t ws_size,
                              hipStream_t stream) {
    const float* hs = (const float*)d_in[0];
    const float* wq = (const float*)d_in[1];
    const float* bq = (const float*)d_in[2];
    const float* wk = (const float*)d_in[3];
    const float* bk = (const float*)d_in[4];
    const float* wv = (const float*)d_in[5];
    const float* bv = (const float*)d_in[6];
    const float* wo = (const float*)d_in[7];
    const float* bo = (const float*)d_in[8];
    float* out = (float*)d_out;

    const size_t NB = (size_t)8192 * 768;
    const size_t WN = (size_t)768 * 768;
    ushort_t* hsb = (ushort_t*)d_ws;        // aliased: becomes AO after QKV GEMMs
    ushort_t* Qb  = hsb + NB;
    ushort_t* Kb  = Qb + NB;
    ushort_t* Vtb = Kb + NB;                // V transposed [48][64][2048]
    ushort_t* wqb = Vtb + NB;
    ushort_t* wkb = wqb + WN;
    ushort_t* wvb = wkb + WN;
    ushort_t* wob = wvb + WN;
    ushort_t* AO  = hsb;                    // hs_bf16 dead once attn runs

    dim3 blk(256);
    convert_bf16<<<dim3(3072, 5), blk, 0, stream>>>(hs, wq, wk, wv, wo,
                                                    hsb, wqb, wkb, wvb, wob);
    gemm_mfma<0><<<dim3(1152), blk, 0, stream>>>(hsb, wqb, wkb, wvb,
                                                 bq, bk, bv, Qb, Kb, Vtb);
    attn_mfma<<<dim3(768), blk, 0, stream>>>(Qb, Kb, Vtb, AO);
    gemm_mfma<1><<<dim3(384), blk, 0, stream>>>(AO, wob, wob, wob,
                                                bo, bo, bo, out, out, out);
}